// Round 3
// baseline (229.881 us; speedup 1.0000x reference)
//
#include <hip/hip_runtime.h>
#include <stdint.h>

// ---------------------------------------------------------------------------
// AttentionBlock: out = hs + (softmax(mask((hs Wq^T+bq)(hs Wk^T+bk)^T /32)) (hs Wv^T+bv)) Wo^T + bo
// B=4, S=2048, D=1024, fp32 in/out. bf16 MFMA compute, fp32 accumulate.
// GEMM engine: per-wave 128x64 output (8x4 frags), 16-MFMA phases,
// 8 phases / 2 K-tiles, half-tile staging, counted vmcnt (never 0 mid-loop).
// WM=2: BM=256,BN=256, 512 thr (2M x 4N waves), LDS 128 KB.
// WM=1: BM=128,BN=256, 256 thr (1M x 4N waves), LDS 96 KB.
// ---------------------------------------------------------------------------

typedef __attribute__((ext_vector_type(8))) short bf16x8;
typedef __attribute__((ext_vector_type(4))) float f32x4;

typedef __attribute__((address_space(3))) void lds_void_t;
typedef __attribute__((address_space(1))) const void glb_void_t;

__device__ __forceinline__ ushort f2bf(float f) {
  uint32_t u = __float_as_uint(f);
  u += 0x7FFF + ((u >> 16) & 1);   // round-to-nearest-even
  return (ushort)(u >> 16);
}
__device__ __forceinline__ float bf2f(ushort u) {
  return __uint_as_float(((uint32_t)u) << 16);
}

// ---------------------------------------------------------------------------
// Convert fp32 inputs (X, Wq, Wk, Wv, Wo) to bf16 workspace copies.
// Last block also concatenates bq|bk into bqk (f32).
// ---------------------------------------------------------------------------
__global__ __launch_bounds__(256) void convert_all(
    const float* __restrict__ X, const float* __restrict__ Wq,
    const float* __restrict__ Wk, const float* __restrict__ Wv,
    const float* __restrict__ Wo, const float* __restrict__ bq,
    const float* __restrict__ bk,
    ushort* __restrict__ Xb, ushort* __restrict__ Wqb, ushort* __restrict__ Wkb,
    ushort* __restrict__ Wvb, ushort* __restrict__ Wob,
    float* __restrict__ bqk) {
  if (blockIdx.x >= 12288) {
#pragma unroll
    for (int u = 0; u < 2; ++u) {
      int idx4 = threadIdx.x * 2 + u;   // 0..511
      int base = idx4 * 4;
      float4 v = (base < 1024) ? *(const float4*)(bq + base)
                               : *(const float4*)(bk + base - 1024);
      *(float4*)(bqk + base) = v;
    }
    return;
  }
  int64_t i = (int64_t)blockIdx.x * blockDim.x + threadIdx.x;  // float4 index
  int64_t o4 = i * 4;
  const float* s; ushort* d; int64_t off;
  if (o4 < 8388608)        { s = X;  d = Xb;  off = o4; }
  else if (o4 < 9437184)   { s = Wq; d = Wqb; off = o4 - 8388608; }
  else if (o4 < 10485760)  { s = Wk; d = Wkb; off = o4 - 9437184; }
  else if (o4 < 11534336)  { s = Wv; d = Wvb; off = o4 - 10485760; }
  else                     { s = Wo; d = Wob; off = o4 - 11534336; }
  float4 v = *(const float4*)(s + off);
  ushort4 o;
  o.x = f2bf(v.x); o.y = f2bf(v.y); o.z = f2bf(v.z); o.w = f2bf(v.w);
  *(ushort4*)(d + off) = o;
}

// ---------------------------------------------------------------------------
// GEMM: C[M,N] = A[M,K] * B[N,K]^T  (row-major bf16, strides lda/ldb)
// MODE: 0 = bf16 out + bias[col]
//       1 = bf16 out + bias[row]
//       2 = bf16 out, * scale (no bias)
//       3 = f32  out + bias[col] + resid[row*ldo+col]
// ---------------------------------------------------------------------------

#define BAR   __builtin_amdgcn_s_barrier()
#define SCHED __builtin_amdgcn_sched_barrier(0)
#define LGKM0 asm volatile("s_waitcnt lgkmcnt(0)" ::: "memory")
#define VMC0  asm volatile("s_waitcnt vmcnt(0)" ::: "memory")

template <int MODE, int WM>
__global__ __launch_bounds__(WM * 256, WM) void gemm8(
    const ushort* __restrict__ Ag, const ushort* __restrict__ Bg,
    void* __restrict__ Og, const float* __restrict__ bias,
    const float* __restrict__ resid,
    int N, int K, int lda, int ldb, int ldo,
    long long sAz, long long sBz, long long sOz, float scale) {
  constexpr int THREADS = WM * 256;
  constexpr int BM = WM * 128;
  __shared__ ushort As[2][BM * 64];
  __shared__ ushort Bs[2][256 * 64];

  const int z = blockIdx.z;
  const ushort* A = Ag + (int64_t)z * sAz;
  const ushort* B = Bg + (int64_t)z * sBz;

  const int tilesN = N >> 8;
  // bijective XCD-aware swizzle (m204); all grids here have nwg % 8 == 0.
  const int nwg = gridDim.x;
  const int q8 = nwg >> 3, r8 = nwg & 7;
  const int xcd = blockIdx.x & 7, sub = blockIdx.x >> 3;
  const int wg = (xcd < r8 ? xcd * (q8 + 1) : r8 * (q8 + 1) + (xcd - r8) * q8) + sub;
  const int tm = wg / tilesN, tn = wg % tilesN;

  const int tid = threadIdx.x;
  const int wid = tid >> 6;
  const int lane = tid & 63;
  const int lr = lane & 15;   // fragment row (A) / col (B) / out col
  const int kq = lane >> 4;   // k-quad
  const int wr = (WM == 2) ? (wid >> 2) * 128 : 0;  // wave row offset
  const int wc = (wid & 3) * 64;                    // wave col offset

  const int64_t abase = (int64_t)tm * BM;
  const int64_t bbase = (int64_t)tn * 256;

  // ---- staging pointers: A 4 slots/thread, B 4 (WM=2) or 8 (WM=1) slots.
  // chunk c = slot*THREADS + tid -> row c>>3, k-slot c&7 (source XOR-swizzled).
#define MKA(s_) (A + (abase + (((s_)*THREADS + tid) >> 3)) * lda + \
                 ((((s_)*THREADS + tid) & 7) ^ ((((s_)*THREADS + tid) >> 3) & 7)) * 8)
#define MKB(s_) (B + (bbase + (((s_)*THREADS + tid) >> 3)) * ldb + \
                 ((((s_)*THREADS + tid) & 7) ^ ((((s_)*THREADS + tid) >> 3) & 7)) * 8)
  const ushort* gA0 = MKA(0); const ushort* gA1 = MKA(1);
  const ushort* gA2 = MKA(2); const ushort* gA3 = MKA(3);
  const ushort* gB0 = MKB(0); const ushort* gB1 = MKB(1);
  const ushort* gB2 = MKB(2); const ushort* gB3 = MKB(3);
  const ushort* gB4 = nullptr; const ushort* gB5 = nullptr;
  const ushort* gB6 = nullptr; const ushort* gB7 = nullptr;
  if constexpr (WM == 1) { gB4 = MKB(4); gB5 = MKB(5); gB6 = MKB(6); gB7 = MKB(7); }
#undef MKA
#undef MKB

#define ST_A(s_, BUF) do { \
    __builtin_amdgcn_global_load_lds((glb_void_t*)gA##s_, \
      (lds_void_t*)((char*)&As[BUF][0] + ((s_) * THREADS + tid) * 16), 16, 0, 0); \
    gA##s_ += 64; } while (0)
#define ST_B(s_, BUF) do { \
    __builtin_amdgcn_global_load_lds((glb_void_t*)gB##s_, \
      (lds_void_t*)((char*)&Bs[BUF][0] + ((s_) * THREADS + tid) * 16), 16, 0, 0); \
    gB##s_ += 64; } while (0)
#define STAGE_BH0(BUF) do { \
    if constexpr (WM == 2) { ST_B(0, BUF); ST_B(1, BUF); } \
    else { ST_B(0, BUF); ST_B(1, BUF); ST_B(2, BUF); ST_B(3, BUF); } } while (0)
#define STAGE_BH1(BUF) do { \
    if constexpr (WM == 2) { ST_B(2, BUF); ST_B(3, BUF); } \
    else { ST_B(4, BUF); ST_B(5, BUF); ST_B(6, BUF); ST_B(7, BUF); } } while (0)
#define VMCG do { \
    if constexpr (WM == 2) { asm volatile("s_waitcnt vmcnt(4)" ::: "memory"); } \
    else { asm volatile("s_waitcnt vmcnt(8)" ::: "memory"); } } while (0)

  // ---- fragment read bases (chunk-swizzled): slot = (ks*4+kq) ^ (lr&7).
  // row&7 == lr&7 for all frags, so the swizzle offset is frag-independent.
  const int rsw0 = (kq ^ (lr & 7)) * 8;
  const int rsw1 = rsw0 ^ 32;
  const ushort* Arp0 = &As[0][(wr + lr) * 64];
  const ushort* Arp1 = &As[1][(wr + lr) * 64];
  const ushort* Brp0 = &Bs[0][(wc + lr) * 64];
  const ushort* Brp1 = &Bs[1][(wc + lr) * 64];

  bf16x8 a[4][2], b[4][2];
  f32x4 acc[8][4];
#pragma unroll
  for (int m = 0; m < 8; ++m)
#pragma unroll
    for (int n = 0; n < 4; ++n) acc[m][n] = (f32x4){0.f, 0.f, 0.f, 0.f};

#define RD_A4(BUF, mb) { \
    const ushort* p_ = (BUF ? Arp1 : Arp0) + (mb) * 1024; \
    a[0][0] = *(const bf16x8*)(p_ + rsw0);        a[0][1] = *(const bf16x8*)(p_ + rsw1); \
    a[1][0] = *(const bf16x8*)(p_ + 1024 + rsw0); a[1][1] = *(const bf16x8*)(p_ + 1024 + rsw1); \
    a[2][0] = *(const bf16x8*)(p_ + 2048 + rsw0); a[2][1] = *(const bf16x8*)(p_ + 2048 + rsw1); \
    a[3][0] = *(const bf16x8*)(p_ + 3072 + rsw0); a[3][1] = *(const bf16x8*)(p_ + 3072 + rsw1); }
#define RD_B2(BUF, nb) { \
    const ushort* p_ = (BUF ? Brp1 : Brp0) + (nb) * 1024; \
    b[nb][0]     = *(const bf16x8*)(p_ + rsw0);        b[nb][1]     = *(const bf16x8*)(p_ + rsw1); \
    b[nb + 1][0] = *(const bf16x8*)(p_ + 1024 + rsw0); b[nb + 1][1] = *(const bf16x8*)(p_ + 1024 + rsw1); }
#define MM2(mi, ni, mg, ng) \
    acc[mg][ng] = __builtin_amdgcn_mfma_f32_16x16x32_bf16(a[mi][0], b[ni][0], acc[mg][ng], 0, 0, 0); \
    acc[mg][ng] = __builtin_amdgcn_mfma_f32_16x16x32_bf16(a[mi][1], b[ni][1], acc[mg][ng], 0, 0, 0);
#define CLUSTER(mb, nb) \
    __builtin_amdgcn_s_setprio(1); \
    MM2(0, nb, mb + 0, nb) MM2(0, nb + 1, mb + 0, nb + 1) \
    MM2(1, nb, mb + 1, nb) MM2(1, nb + 1, mb + 1, nb + 1) \
    MM2(2, nb, mb + 2, nb) MM2(2, nb + 1, mb + 2, nb + 1) \
    MM2(3, nb, mb + 3, nb) MM2(3, nb + 1, mb + 3, nb + 1) \
    __builtin_amdgcn_s_setprio(0);

  // ---- prologue: T0.A->buf0, T0.B->buf0, T1.B->buf1; gate leaves T1.B in flight
  ST_A(0, 0); ST_A(1, 0); ST_A(2, 0); ST_A(3, 0);
  STAGE_BH0(0); STAGE_BH1(0);
  STAGE_BH0(1); STAGE_BH1(1);
  VMCG; BAR; SCHED;

  const int NI = K >> 7;  // 2 BK=64 tiles per iteration
  for (int it = 0; it < NI; ++it) {
    const bool last = (it == NI - 1);
    // ph0 (buf0): rd a[m0-3], b01; stage Ah0(T1)->buf1
    RD_A4(0, 0) RD_B2(0, 0)
    ST_A(0, 1); ST_A(1, 1);
    BAR; LGKM0; SCHED;
    CLUSTER(0, 0)
    SCHED; BAR;
    // ph1: rd b23; stage Ah1(T1)->buf1
    RD_B2(0, 2)
    ST_A(2, 1); ST_A(3, 1);
    BAR; LGKM0; SCHED;
    CLUSTER(0, 2)
    SCHED; BAR;
    // ph2: rd a[m4-7]; stage Bh0(T2)->buf0
    RD_A4(0, 4)
    if (!last) { STAGE_BH0(0); }
    BAR; LGKM0; SCHED;
    CLUSTER(4, 2)
    SCHED; BAR;
    // ph3: stage Bh1(T2)->buf0; gate (T1 complete before ph4 reads buf1)
    if (!last) { STAGE_BH1(0); }
    BAR; SCHED;
    CLUSTER(4, 0)
    SCHED;
    if (last) { VMC0; } else { VMCG; }
    BAR;
    // ph4 (buf1): rd a[m0-3], b01; stage Ah0(T2)->buf0
    RD_A4(1, 0) RD_B2(1, 0)
    if (!last) { ST_A(0, 0); ST_A(1, 0); }
    BAR; LGKM0; SCHED;
    CLUSTER(0, 0)
    SCHED; BAR;
    // ph5: rd b23; stage Ah1(T2)->buf0
    RD_B2(1, 2)
    if (!last) { ST_A(2, 0); ST_A(3, 0); }
    BAR; LGKM0; SCHED;
    CLUSTER(0, 2)
    SCHED; BAR;
    // ph6: rd a[m4-7]; stage Bh0(T3)->buf1
    RD_A4(1, 4)
    if (!last) { STAGE_BH0(1); }
    BAR; LGKM0; SCHED;
    CLUSTER(4, 2)
    SCHED; BAR;
    // ph7: stage Bh1(T3)->buf1; gate (T2 complete before next ph0 reads buf0)
    if (!last) { STAGE_BH1(1); }
    BAR; SCHED;
    CLUSTER(4, 0)
    SCHED;
    if (!last) { VMCG; }
    BAR;
  }

  // ---- epilogue. C/D frag layout: col = lane&15, row = (lane>>4)*4 + reg.
#pragma unroll
  for (int m = 0; m < 8; ++m) {
#pragma unroll
    for (int n = 0; n < 4; ++n) {
      int c = tn * 256 + wc + n * 16 + lr;
      int r0 = tm * BM + wr + m * 16 + kq * 4;
#pragma unroll
      for (int i = 0; i < 4; ++i) {
        int rrow = r0 + i;
        float v = acc[m][n][i];
        int64_t oo = (int64_t)z * sOz + (int64_t)rrow * ldo + c;
        if constexpr (MODE == 0) {
          v += bias[c];
          ((ushort*)Og)[oo] = f2bf(v);
        } else if constexpr (MODE == 1) {
          v += bias[rrow];
          ((ushort*)Og)[oo] = f2bf(v);
        } else if constexpr (MODE == 2) {
          v *= scale;
          ((ushort*)Og)[oo] = f2bf(v);
        } else {
          v += bias[c] + resid[(int64_t)rrow * ldo + c];
          ((float*)Og)[oo] = v;
        }
      }
    }
  }
#undef RD_A4
#undef RD_B2
#undef MM2
#undef CLUSTER
#undef ST_A
#undef ST_B
#undef STAGE_BH0
#undef STAGE_BH1
#undef VMCG
}

// ---------------------------------------------------------------------------
// Row softmax with key-padding mask, in place on bf16 P[8192][2048].
// ---------------------------------------------------------------------------
__global__ __launch_bounds__(256) void softmax_rows(ushort* __restrict__ P,
                                                    const int* __restrict__ mask) {
  const int row = blockIdx.x;       // 0..8191  (b*2048 + q)
  const int b = row >> 11;
  ushort* prow = P + (int64_t)row * 2048;
  const int* mrow = mask + (b << 11);
  const int tid = threadIdx.x;
  const int wid = tid >> 6, lane = tid & 63;

  float v[8];
#pragma unroll
  for (int t = 0; t < 2; ++t) {
    int c4 = t * 256 + tid;  // ushort4 index, 512 per row
    ushort4 pv = *(const ushort4*)(prow + c4 * 4);
    int4 mv = *(const int4*)(mrow + c4 * 4);
    v[t * 4 + 0] = mv.x ? bf2f(pv.x) : -1e10f;
    v[t * 4 + 1] = mv.y ? bf2f(pv.y) : -1e10f;
    v[t * 4 + 2] = mv.z ? bf2f(pv.z) : -1e10f;
    v[t * 4 + 3] = mv.w ? bf2f(pv.w) : -1e10f;
  }
  float mx = -3e38f;
#pragma unroll
  for (int j = 0; j < 8; ++j) mx = fmaxf(mx, v[j]);
#pragma unroll
  for (int off = 32; off; off >>= 1) mx = fmaxf(mx, __shfl_xor(mx, off));
  __shared__ float redm[4];
  __shared__ float reds[4];
  if (lane == 0) redm[wid] = mx;
  __syncthreads();
  mx = fmaxf(fmaxf(redm[0], redm[1]), fmaxf(redm[2], redm[3]));

  float e[8];
  float s = 0.f;
#pragma unroll
  for (int j = 0; j < 8; ++j) {
    e[j] = __expf(v[j] - mx);
    s += e[j];
  }
#pragma unroll
  for (int off = 32; off; off >>= 1) s += __shfl_xor(s, off);
  if (lane == 0) reds[wid] = s;
  __syncthreads();
  s = reds[0] + reds[1] + reds[2] + reds[3];
  float inv = 1.0f / s;

#pragma unroll
  for (int t = 0; t < 2; ++t) {
    int c4 = t * 256 + tid;
    ushort4 o;
    o.x = f2bf(e[t * 4 + 0] * inv);
    o.y = f2bf(e[t * 4 + 1] * inv);
    o.z = f2bf(e[t * 4 + 2] * inv);
    o.w = f2bf(e[t * 4 + 3] * inv);
    *(ushort4*)(prow + c4 * 4) = o;
  }
}

// ---------------------------------------------------------------------------
// Host-side launch
// ---------------------------------------------------------------------------
extern "C" void kernel_launch(void* const* d_in, const int* in_sizes, int n_in,
                              void* d_out, int out_size, void* d_ws, size_t ws_size,
                              hipStream_t stream) {
  const float* hs = (const float*)d_in[0];
  const int* mask = (const int*)d_in[1];
  const float* Wq = (const float*)d_in[2];
  const float* bq = (const float*)d_in[3];
  const float* Wk = (const float*)d_in[4];
  const float* bk = (const float*)d_in[5];
  const float* Wv = (const float*)d_in[6];
  const float* bv = (const float*)d_in[7];
  const float* Wo = (const float*)d_in[8];
  const float* bo = (const float*)d_in[9];
  float* out = (float*)d_out;
  char* w = (char*)d_ws;

  // Workspace layout (bytes), total 120 MiB:
  ushort* Xb   = (ushort*)(w + 0);          // [8192][1024] bf16
  ushort* Wqb  = (ushort*)(w + 16777216);   // [2048][1024]  (Wq ; Wk adjacent)
  ushort* Wkb  = (ushort*)(w + 18874368);
  ushort* Wvb  = (ushort*)(w + 20971520);
  ushort* Wob  = (ushort*)(w + 23068672);
  ushort* QKb  = (ushort*)(w + 25165824);   // [8192][2048]  (cols 0..1023 Q, 1024.. K)
  ushort* Vt   = (ushort*)(w + 58720256);   // [1024][8192]  (V^T, batches in cols)
  ushort* P    = (ushort*)(w + 75497472);   // [4][2048][2048]
  float*  bqk  = (float*)(w + 75497472);    // 2048 f32, dead before P is written
  ushort* AO   = (ushort*)(w + 109051904);  // [4][2048][1024]

  // 1. fp32 -> bf16 packing (+ bias concat into bqk)
  convert_all<<<12289, 256, 0, stream>>>(hs, Wq, Wk, Wv, Wo, bq, bk,
                                         Xb, Wqb, Wkb, Wvb, Wob, bqk);

  // 2. [Q|K] = X [Wq;Wk]^T + [bq|bk]   (M=8192, N=2048, K=1024) -> 32x8 = 256 blk
  gemm8<0, 2><<<dim3(256, 1, 1), 512, 0, stream>>>(Xb, Wqb, QKb, bqk, nullptr,
      2048, 1024, 1024, 1024, 2048, 0, 0, 0, 1.f);

  // 3. V^T = Wv X^T + bv  (M=1024, N=8192, row bias) -> 8x32 = 256 blk (WM=1)
  gemm8<1, 1><<<dim3(256, 1, 1), 256, 0, stream>>>(Wvb, Xb, Vt, bv, nullptr,
      8192, 1024, 1024, 1024, 8192, 0, 0, 0, 1.f);

  // 4. P = (Q K^T) / 32  per batch (M=N=2048, K=1024) -> 8x8x4 = 256 blk
  gemm8<2, 2><<<dim3(64, 1, 4), 512, 0, stream>>>(QKb, QKb + 1024, P, nullptr, nullptr,
      2048, 1024, 2048, 2048, 2048,
      (long long)2048 * 2048, (long long)2048 * 2048, (long long)2048 * 2048,
      0.03125f);

  // 5. masked softmax rows, in place on P
  softmax_rows<<<8192, 256, 0, stream>>>(P, mask);

  // 6. AO = P V  per batch (M=2048, N=1024, K=2048) -> 16x4x4 = 256 blk (WM=1)
  gemm8<2, 1><<<dim3(64, 1, 4), 256, 0, stream>>>(P, Vt, AO, nullptr, nullptr,
      1024, 2048, 2048, 8192, 1024,
      (long long)2048 * 2048, (long long)2048, (long long)2048 * 1024, 1.f);

  // 7. out = AO Wo^T + bo + hs  (fp32 out, M=8192, N=1024) -> 64x4 = 256 blk (WM=1)
  gemm8<3, 1><<<dim3(256, 1, 1), 256, 0, stream>>>(AO, Wob, (void*)out, bo, hs,
      1024, 1024, 1024, 1024, 1024, 0, 0, 0, 1.f);
}